// Round 1
// baseline (357.090 us; speedup 1.0000x reference)
//
#include <hip/hip_runtime.h>
#include <stdint.h>
#include <math.h>

// cdist-attention, bf16 MFMA pipeline:
//   castk:        fp32 -> bf16 (RNE)
//   gemm_bt<0>:   C_bf16 = A(MxK) . B(NxK)^T   (both operands row-major over K)
//   rowreduce<1>: row sum-of-squares (q2,k2)
//   gemm_bt<1>:   E = exp(sqrt(max(q2+k2-2*QK,0))/sqrt(768)) as bf16
//   rowreduce<0>: l = rowsum(E)
//   gemm_bt<2>:   out_f32 = (E . V^T^T)/l
// Tile: 128x128, BK=32, 4 waves (2x2 of 64x64), mfma_f32_16x16x32_bf16,
// global_load_lds dwordx4 staging (linear LDS), 2-barrier K-loop.

typedef __attribute__((ext_vector_type(8))) __bf16 bf16x8;
typedef __attribute__((ext_vector_type(4))) float f32x4;

__device__ __forceinline__ unsigned short f2b(float f) {
    unsigned u = __float_as_uint(f);
    unsigned r = 0x7fffu + ((u >> 16) & 1u);
    return (unsigned short)((u + r) >> 16);
}
__device__ __forceinline__ float b2f(unsigned short h) {
    return __uint_as_float(((unsigned)h) << 16);
}

__global__ __launch_bounds__(256) void castk(const float* __restrict__ src,
                                             unsigned short* __restrict__ dst, int n4) {
    int i = blockIdx.x * 256 + threadIdx.x;
    if (i >= n4) return;
    float4 v = ((const float4*)src)[i];
    ushort4 o;
    o.x = f2b(v.x); o.y = f2b(v.y); o.z = f2b(v.z); o.w = f2b(v.w);
    ((ushort4*)dst)[i] = o;
}

// MODE 0: row sum; MODE 1: row sum of squares. One wave per row.
template <int MODE>
__global__ __launch_bounds__(256) void rowreduce(const unsigned short* __restrict__ X,
                                                 int L, int rows, float* __restrict__ out) {
    int w = threadIdx.x >> 6, lane = threadIdx.x & 63;
    int row = blockIdx.x * 4 + w;
    if (row >= rows) return;
    const unsigned short* xr = X + (size_t)row * L;
    float s = 0.f;
    int passes = L >> 8;  // 256 elems per pass (64 lanes x 4)
    for (int p = 0; p < passes; ++p) {
        ushort4 u = *(const ushort4*)(xr + (p << 8) + lane * 4);
        float a = b2f(u.x), b = b2f(u.y), c = b2f(u.z), d = b2f(u.w);
        s += MODE ? (a * a + b * b + c * c + d * d) : (a + b + c + d);
    }
#pragma unroll
    for (int o = 32; o > 0; o >>= 1) s += __shfl_down(s, o);
    if (lane == 0) out[row] = s;
}

// C[m][n] = sum_k A[m][k]*B[n][k].  A: (z*sA + m*lda + k), B: (z*sB + n*ldb + k).
// EPI 0: store bf16.  EPI 1: scores epilogue (aux1=q2 rows, aux2=k2 cols, invs).
// EPI 2: store f32 = acc / aux1[row].
template <int EPI>
__global__ __launch_bounds__(256) void gemm_bt(
    const unsigned short* __restrict__ A, int lda, long long sA,
    const unsigned short* __restrict__ B, int ldb, long long sB,
    void* __restrict__ Cv, int ldc, long long sC,
    int Kd,
    const float* __restrict__ aux1, int sAux1,
    const float* __restrict__ aux2, int sAux2,
    float invs) {
    __shared__ unsigned short As[128 * 32];
    __shared__ unsigned short Bs[128 * 32];

    const int z = blockIdx.z;
    const unsigned short* Ab = A + (size_t)z * sA;
    const unsigned short* Bb = B + (size_t)z * sB;
    const int i0 = blockIdx.y * 128;
    const int j0 = blockIdx.x * 128;
    const int tid = threadIdx.x;
    const int w = tid >> 6, lane = tid & 63;
    const int wr = w >> 1, wc = w & 1;

    f32x4 acc[4][4];
    const f32x4 zero = {0.f, 0.f, 0.f, 0.f};
#pragma unroll
    for (int a = 0; a < 4; ++a)
#pragma unroll
        for (int b = 0; b < 4; ++b) acc[a][b] = zero;

    const int c16 = lane & 15;
    const int kq = lane >> 4;  // 0..3
    const int nk = Kd >> 5;

    for (int kt = 0; kt < nk; ++kt) {
        const int k0 = kt << 5;
        // stage 128x32 bf16 A-tile and B-tile; LDS linear in lane order
#pragma unroll
        for (int is = 0; is < 2; ++is) {
            const int flat = w * 128 + is * 64 + lane;  // 0..511 (16B units)
            const int row = flat >> 2;
            const int sl = flat & 3;
            const unsigned short* ga = Ab + (size_t)(i0 + row) * lda + k0 + sl * 8;
            __builtin_amdgcn_global_load_lds(
                (const __attribute__((address_space(1))) unsigned int*)ga,
                (__attribute__((address_space(3))) unsigned int*)(&As[flat * 8]), 16, 0, 0);
            const unsigned short* gb = Bb + (size_t)(j0 + row) * ldb + k0 + sl * 8;
            __builtin_amdgcn_global_load_lds(
                (const __attribute__((address_space(1))) unsigned int*)gb,
                (__attribute__((address_space(3))) unsigned int*)(&Bs[flat * 8]), 16, 0, 0);
        }
        asm volatile("s_waitcnt vmcnt(0)" ::: "memory");
        __syncthreads();

        bf16x8 af[4], bfv[4];
#pragma unroll
        for (int mi = 0; mi < 4; ++mi) {
            const int ra = wr * 64 + mi * 16 + c16;
            af[mi] = *(const bf16x8*)(&As[ra * 32 + kq * 8]);
        }
#pragma unroll
        for (int ni = 0; ni < 4; ++ni) {
            const int rb = wc * 64 + ni * 16 + c16;
            bfv[ni] = *(const bf16x8*)(&Bs[rb * 32 + kq * 8]);
        }
#pragma unroll
        for (int mi = 0; mi < 4; ++mi)
#pragma unroll
            for (int ni = 0; ni < 4; ++ni)
                acc[mi][ni] = __builtin_amdgcn_mfma_f32_16x16x32_bf16(af[mi], bfv[ni],
                                                                      acc[mi][ni], 0, 0, 0);
        __syncthreads();
    }

    // C/D layout (m89/m91-verified): col = lane&15, row = (lane>>4)*4 + reg
    const int r4 = kq * 4;
    if constexpr (EPI == 0) {
        unsigned short* C = (unsigned short*)Cv + (size_t)z * sC;
#pragma unroll
        for (int mi = 0; mi < 4; ++mi)
#pragma unroll
            for (int ni = 0; ni < 4; ++ni) {
                const int row = i0 + wr * 64 + mi * 16 + r4;
                const int col = j0 + wc * 64 + ni * 16 + c16;
#pragma unroll
                for (int r = 0; r < 4; ++r)
                    C[(size_t)(row + r) * ldc + col] = f2b(acc[mi][ni][r]);
            }
    } else if constexpr (EPI == 1) {
        unsigned short* C = (unsigned short*)Cv + (size_t)z * sC;
        const float* q2b = aux1 + (size_t)z * sAux1;
        const float* k2b = aux2 + (size_t)z * sAux2;
#pragma unroll
        for (int mi = 0; mi < 4; ++mi)
#pragma unroll
            for (int ni = 0; ni < 4; ++ni) {
                const int row = i0 + wr * 64 + mi * 16 + r4;
                const int col = j0 + wc * 64 + ni * 16 + c16;
                const float k2v = k2b[col];
#pragma unroll
                for (int r = 0; r < 4; ++r) {
                    float d2 = q2b[row + r] + k2v - 2.0f * acc[mi][ni][r];
                    float e = __expf(sqrtf(fmaxf(d2, 0.f)) * invs);
                    C[(size_t)(row + r) * ldc + col] = f2b(e);
                }
            }
    } else {
        float* C = (float*)Cv + (size_t)z * sC;
        const float* lb = aux1 + (size_t)z * sAux1;
#pragma unroll
        for (int mi = 0; mi < 4; ++mi)
#pragma unroll
            for (int ni = 0; ni < 4; ++ni) {
                const int row = i0 + wr * 64 + mi * 16 + r4;
                const int col = j0 + wc * 64 + ni * 16 + c16;
#pragma unroll
                for (int r = 0; r < 4; ++r)
                    C[(size_t)(row + r) * ldc + col] = acc[mi][ni][r] / lb[row + r];
            }
    }
}

extern "C" void kernel_launch(void* const* d_in, const int* in_sizes, int n_in,
                              void* d_out, int out_size, void* d_ws, size_t ws_size,
                              hipStream_t stream) {
    const float* x = (const float*)d_in[0];
    const float* Wq = (const float*)d_in[1];
    const float* Wk = (const float*)d_in[2];
    const float* Wv = (const float*)d_in[3];
    const int Bz = 8, S = 2048, D = 768, F = 768;
    const int BS = Bz * S;  // 16384

    const size_t szX = (size_t)BS * D * 2;      // 25,165,824  (also Q/K/VT size)
    const size_t szW = (size_t)F * D * 2;       // 1,179,648
    const size_t szE = (size_t)Bz * S * S * 2;  // 67,108,864

    char* p = (char*)d_ws;
    unsigned short* xb = (unsigned short*)p;  p += szX;
    unsigned short* Wqb = (unsigned short*)p; p += szW;  // Wqb/Wkb contiguous -> one z-strided launch
    unsigned short* Wkb = (unsigned short*)p; p += szW;
    unsigned short* Wvb = (unsigned short*)p; p += szW;
    unsigned short* Qm = (unsigned short*)p;  p += szX;  // Q/K contiguous
    unsigned short* Km = (unsigned short*)p;  p += szX;
    unsigned short* VT = (unsigned short*)p;  p += szX;  // [F][BS]
    unsigned short* E = (unsigned short*)p;   p += szE;  // [Bz][S][S]
    float* q2 = (float*)p;   p += (size_t)BS * 4;
    float* k2 = (float*)p;   p += (size_t)BS * 4;
    float* lsum = (float*)p; p += (size_t)BS * 4;
    if ((size_t)(p - (char*)d_ws) > ws_size) return;  // ~164 MiB scratch required

    const float invs = 1.0f / sqrtf(768.0f);

    // 1) casts
    castk<<<(BS * D / 4 + 255) / 256, 256, 0, stream>>>(x, xb, BS * D / 4);
    castk<<<(F * D / 4 + 255) / 256, 256, 0, stream>>>(Wq, Wqb, F * D / 4);
    castk<<<(F * D / 4 + 255) / 256, 256, 0, stream>>>(Wk, Wkb, F * D / 4);
    castk<<<(F * D / 4 + 255) / 256, 256, 0, stream>>>(Wv, Wvb, F * D / 4);

    // 2) Q,K = x . W^T  (z=0 -> Wq, z=1 -> Wk; outputs Qm, Km)
    gemm_bt<0><<<dim3(F / 128, BS / 128, 2), 256, 0, stream>>>(
        xb, D, 0,
        Wqb, D, (long long)F * D,
        Qm, F, (long long)BS * F,
        D, nullptr, 0, nullptr, 0, 0.f);

    //    V^T = Wv . x^T   -> VT[f][s]
    gemm_bt<0><<<dim3(BS / 128, F / 128, 1), 256, 0, stream>>>(
        Wvb, D, 0,
        xb, D, 0,
        VT, BS, 0,
        D, nullptr, 0, nullptr, 0, 0.f);

    // 3) row norms of Q,K (from bf16 values, consistent with the MFMA dot)
    rowreduce<1><<<BS / 4, 256, 0, stream>>>(Qm, F, BS, q2);
    rowreduce<1><<<BS / 4, 256, 0, stream>>>(Km, F, BS, k2);

    // 4) E = exp(sqrt(max(q2+k2-2*Q.K^T,0))*invs)  (bf16, per batch)
    gemm_bt<1><<<dim3(S / 128, S / 128, Bz), 256, 0, stream>>>(
        Qm, F, (long long)S * F,
        Km, F, (long long)S * F,
        E, S, (long long)S * S,
        F, q2, S, k2, S, invs);

    // 5) l = rowsum(E)
    rowreduce<0><<<BS / 4, 256, 0, stream>>>(E, S, BS, lsum);

    // 6) out = (E . V) / l   (B-operand = VT rows, offset z*S columns)
    gemm_bt<2><<<dim3(F / 128, S / 128, Bz), 256, 0, stream>>>(
        E, S, (long long)S * S,
        VT, BS, (long long)S,
        d_out, F, (long long)S * F,
        S, lsum, S, nullptr, 0, 0.f);
}

// Round 2
// 324.187 us; speedup vs baseline: 1.1015x; 1.1015x over previous
//
#include <hip/hip_runtime.h>
#include <stdint.h>
#include <math.h>

// cdist-attention, bf16 MFMA pipeline, 256x256 deep-pipelined GEMM core:
//   castk:         fp32 -> bf16 (RNE)
//   gemm256<0>:    C_bf16 = A(MxK) . B(NxK)^T
//   rowreduce<1>:  row sum-of-squares (q2,k2)
//   gemm256<1>:    E = exp(sqrt(max(q2+k2-2*QK,0))/sqrt(768)) as bf16
//   rowreduce<0>:  l = rowsum(E)
//   gemm256<2>:    out_f32 = (E . V) / l
//
// GEMM core: BM=BN=256, ring of 4 K=32 sub-tiles (128 KiB LDS), 8 waves
// (2Mx4N, 128x64 C per wave), 2 phases/sub-tile of 16 MFMA, global_load_lds
// staging 3 sub-tiles ahead (counted vmcnt(8), never 0 in steady state),
// raw s_barrier, setprio around MFMA, T2 chunk-XOR swizzle via pre-swizzled
// global source + swizzled ds_read (2-way banks = free).

typedef __attribute__((ext_vector_type(8))) __bf16 bf16x8;
typedef __attribute__((ext_vector_type(4))) float f32x4;

__device__ __forceinline__ unsigned short f2b(float f) {
    unsigned u = __float_as_uint(f);
    unsigned r = 0x7fffu + ((u >> 16) & 1u);
    return (unsigned short)((u + r) >> 16);
}
__device__ __forceinline__ float b2f(unsigned short h) {
    return __uint_as_float(((unsigned)h) << 16);
}

__device__ __forceinline__ void wg_barrier() {
    asm volatile("" ::: "memory");
    __builtin_amdgcn_s_barrier();
    asm volatile("" ::: "memory");
}

__device__ __forceinline__ void glds16(const unsigned short* src, unsigned short* dst) {
    __builtin_amdgcn_global_load_lds(
        (const __attribute__((address_space(1))) unsigned int*)src,
        (__attribute__((address_space(3))) unsigned int*)dst, 16, 0, 0);
}

__global__ __launch_bounds__(256) void castk(const float* __restrict__ src,
                                             unsigned short* __restrict__ dst, int n4) {
    int i = blockIdx.x * 256 + threadIdx.x;
    if (i >= n4) return;
    float4 v = ((const float4*)src)[i];
    ushort4 o;
    o.x = f2b(v.x); o.y = f2b(v.y); o.z = f2b(v.z); o.w = f2b(v.w);
    ((ushort4*)dst)[i] = o;
}

// MODE 0: row sum; MODE 1: row sum of squares. One wave per row.
template <int MODE>
__global__ __launch_bounds__(256) void rowreduce(const unsigned short* __restrict__ X,
                                                 int L, int rows, float* __restrict__ out) {
    int w = threadIdx.x >> 6, lane = threadIdx.x & 63;
    int row = blockIdx.x * 4 + w;
    if (row >= rows) return;
    const unsigned short* xr = X + (size_t)row * L;
    float s = 0.f;
    int passes = L >> 8;
    for (int p = 0; p < passes; ++p) {
        ushort4 u = *(const ushort4*)(xr + (p << 8) + lane * 4);
        float a = b2f(u.x), b = b2f(u.y), c = b2f(u.z), d = b2f(u.w);
        s += MODE ? (a * a + b * b + c * c + d * d) : (a + b + c + d);
    }
#pragma unroll
    for (int o = 32; o > 0; o >>= 1) s += __shfl_down(s, o);
    if (lane == 0) out[row] = s;
}

// C[m][n] = sum_k A[m][k]*B[n][k].
// EPI 0: store bf16.  EPI 1: scores epilogue (aux1=q2 rows, aux2=k2 cols, invs).
// EPI 2: store f32 = acc / aux1[row].
template <int EPI>
__global__ __launch_bounds__(512, 2) void gemm256(
    const unsigned short* __restrict__ A, int lda, long long sA,
    const unsigned short* __restrict__ B, int ldb, long long sB,
    void* __restrict__ Cv, int ldc, long long sC,
    int Kd,
    const float* __restrict__ aux1, int sAux1,
    const float* __restrict__ aux2, int sAux2,
    float invs) {
    // ring of 4 sub-tiles, each [128 ldsrows][8 chunks of 16B] = 16 KiB
    __shared__ unsigned short As[4 * 8192];
    __shared__ unsigned short Bs[4 * 8192];

    const int z = blockIdx.z;
    const unsigned short* __restrict__ Ab = A + (size_t)z * sA;
    const unsigned short* __restrict__ Bb = B + (size_t)z * sB;
    const int i0 = blockIdx.y * 256;
    const int j0 = blockIdx.x * 256;
    const int tid = threadIdx.x;
    const int w = tid >> 6, lane = tid & 63;
    const int wr = w >> 2, wc = w & 3;          // 2 x 4 wave grid
    const int c16 = lane & 15, kq = lane >> 4;  // frag col / k-quad

    // ---- staging geometry: 2 chunks per operand per thread ----
    // LDS chunk f <-> (ldsrow=f>>3, stored chunk c=f&7); logical chunk
    // c_log = c ^ (ldsrow&7) (involution); logical element:
    // row = ldsrow*2 + (c_log>>2), k = (c_log&3)*8.
    const int f0 = tid, f1 = 512 + tid;
    const int lr0 = f0 >> 3, lr1 = f1 >> 3;
    const int cl0 = (f0 & 7) ^ (lr0 & 7), cl1 = (f1 & 7) ^ (lr1 & 7);
    const int ro0 = lr0 * 2 + (cl0 >> 2), ro1 = lr1 * 2 + (cl1 >> 2);
    const int ko0 = (cl0 & 3) * 8, ko1 = (cl1 & 3) * 8;
    const unsigned short* pA0 = Ab + (size_t)(i0 + ro0) * lda + ko0;
    const unsigned short* pA1 = Ab + (size_t)(i0 + ro1) * lda + ko1;
    const unsigned short* pB0 = Bb + (size_t)(j0 + ro0) * ldb + ko0;
    const unsigned short* pB1 = Bb + (size_t)(j0 + ro1) * ldb + ko1;

#define STAGE_A(s) { const int sb_ = ((s) & 3) * 8192; \
    glds16(pA0 + (s) * 32, &As[sb_ + f0 * 8]); \
    glds16(pA1 + (s) * 32, &As[sb_ + f1 * 8]); }
#define STAGE_B(s) { const int sb_ = ((s) & 3) * 8192; \
    glds16(pB0 + (s) * 32, &Bs[sb_ + f0 * 8]); \
    glds16(pB1 + (s) * 32, &Bs[sb_ + f1 * 8]); }

    f32x4 acc[8][4];
    const f32x4 zero = {0.f, 0.f, 0.f, 0.f};
#pragma unroll
    for (int i = 0; i < 8; ++i)
#pragma unroll
        for (int j = 0; j < 4; ++j) acc[i][j] = zero;

    // ---- read geometry (swizzled): element (rl, kq*8) is at
    // ldsrow = rl>>1, chunk = ((rl&1)*4 + kq) ^ (ldsrow&7)
    const int clog = (c16 & 1) * 4 + kq;  // per-thread constant
    const int rA = wr * 128 + c16;        // + mi*16
    const int rB = wc * 64 + c16;         // + ni*16
#define LDSIDX(sbase, rl) ((sbase) + ((((rl) >> 1)) << 6) + ((clog ^ (((rl) >> 1) & 7)) << 3))

    const int NT = Kd >> 5;  // K=32 sub-tiles; requires NT >= 3

    // prologue: stage sub-tiles 0,1,2 (12 loads/thread)
    STAGE_A(0) STAGE_B(0) STAGE_A(1) STAGE_B(1) STAGE_A(2) STAGE_B(2)
    asm volatile("s_waitcnt vmcnt(8)" ::: "memory");  // sub-tile 0 landed
    wg_barrier();

    for (int s = 0; s < NT; ++s) {
        const int sb = (s & 3) * 8192;
        const int rem = NT - 1 - s;
        // ---- phase 0: stage A(s+3) -> slot (s-1)&3 (dead); read A-top + B;
        //              MFMA top half ----
        if (rem >= 3) STAGE_A(s + 3)
        bf16x8 a0[4], b0[4];
#pragma unroll
        for (int mi = 0; mi < 4; ++mi)
            a0[mi] = *(const bf16x8*)(&As[LDSIDX(sb, rA + mi * 16)]);
#pragma unroll
        for (int ni = 0; ni < 4; ++ni)
            b0[ni] = *(const bf16x8*)(&Bs[LDSIDX(sb, rB + ni * 16)]);
        wg_barrier();
        __builtin_amdgcn_s_setprio(1);
#pragma unroll
        for (int mi = 0; mi < 4; ++mi)
#pragma unroll
            for (int ni = 0; ni < 4; ++ni)
                acc[mi][ni] = __builtin_amdgcn_mfma_f32_16x16x32_bf16(
                    a0[mi], b0[ni], acc[mi][ni], 0, 0, 0);
        __builtin_amdgcn_s_setprio(0);
        wg_barrier();
        // ---- phase 1: stage B(s+3); read A-bottom; MFMA bottom half ----
        if (rem >= 3) STAGE_B(s + 3)
        bf16x8 a1[4];
#pragma unroll
        for (int mi = 0; mi < 4; ++mi)
            a1[mi] = *(const bf16x8*)(&As[LDSIDX(sb, rA + 64 + mi * 16)]);
        wg_barrier();
        __builtin_amdgcn_s_setprio(1);
#pragma unroll
        for (int mi = 0; mi < 4; ++mi)
#pragma unroll
            for (int ni = 0; ni < 4; ++ni)
                acc[4 + mi][ni] = __builtin_amdgcn_mfma_f32_16x16x32_bf16(
                    a1[mi], b0[ni], acc[4 + mi][ni], 0, 0, 0);
        __builtin_amdgcn_s_setprio(0);
        // boundary: force sub-tile s+1 landed; keep up to 8 (s+2,s+3) in flight
        if (rem >= 3)      { asm volatile("s_waitcnt vmcnt(8)" ::: "memory"); }
        else if (rem == 2) { asm volatile("s_waitcnt vmcnt(4)" ::: "memory"); }
        else               { asm volatile("s_waitcnt vmcnt(0)" ::: "memory"); }
        wg_barrier();
    }

    // C/D layout: col = lane&15, row = (lane>>4)*4 + reg
    const int r4 = kq * 4;
    if constexpr (EPI == 0) {
        unsigned short* C = (unsigned short*)Cv + (size_t)z * sC;
#pragma unroll
        for (int mi = 0; mi < 8; ++mi)
#pragma unroll
            for (int ni = 0; ni < 4; ++ni) {
                const int row = i0 + wr * 128 + mi * 16 + r4;
                const int col = j0 + wc * 64 + ni * 16 + c16;
#pragma unroll
                for (int r = 0; r < 4; ++r)
                    C[(size_t)(row + r) * ldc + col] = f2b(acc[mi][ni][r]);
            }
    } else if constexpr (EPI == 1) {
        unsigned short* C = (unsigned short*)Cv + (size_t)z * sC;
        const float* q2b = aux1 + (size_t)z * sAux1;
        const float* k2b = aux2 + (size_t)z * sAux2;
#pragma unroll
        for (int mi = 0; mi < 8; ++mi)
#pragma unroll
            for (int ni = 0; ni < 4; ++ni) {
                const int row = i0 + wr * 128 + mi * 16 + r4;
                const int col = j0 + wc * 64 + ni * 16 + c16;
                const float k2v = k2b[col];
#pragma unroll
                for (int r = 0; r < 4; ++r) {
                    float d2 = q2b[row + r] + k2v - 2.0f * acc[mi][ni][r];
                    float e = __expf(sqrtf(fmaxf(d2, 0.f)) * invs);
                    C[(size_t)(row + r) * ldc + col] = f2b(e);
                }
            }
    } else {
        float* C = (float*)Cv + (size_t)z * sC;
        const float* lb = aux1 + (size_t)z * sAux1;
#pragma unroll
        for (int mi = 0; mi < 8; ++mi)
#pragma unroll
            for (int ni = 0; ni < 4; ++ni) {
                const int row = i0 + wr * 128 + mi * 16 + r4;
                const int col = j0 + wc * 64 + ni * 16 + c16;
#pragma unroll
                for (int r = 0; r < 4; ++r)
                    C[(size_t)(row + r) * ldc + col] = acc[mi][ni][r] / lb[row + r];
            }
    }
#undef STAGE_A
#undef STAGE_B
#undef LDSIDX
}

extern "C" void kernel_launch(void* const* d_in, const int* in_sizes, int n_in,
                              void* d_out, int out_size, void* d_ws, size_t ws_size,
                              hipStream_t stream) {
    const float* x = (const float*)d_in[0];
    const float* Wq = (const float*)d_in[1];
    const float* Wk = (const float*)d_in[2];
    const float* Wv = (const float*)d_in[3];
    const int Bz = 8, S = 2048, D = 768, F = 768;
    const int BS = Bz * S;  // 16384

    const size_t szX = (size_t)BS * D * 2;
    const size_t szW = (size_t)F * D * 2;
    const size_t szE = (size_t)Bz * S * S * 2;

    char* p = (char*)d_ws;
    unsigned short* xb = (unsigned short*)p;  p += szX;
    unsigned short* Wqb = (unsigned short*)p; p += szW;
    unsigned short* Wkb = (unsigned short*)p; p += szW;
    unsigned short* Wvb = (unsigned short*)p; p += szW;
    unsigned short* Qm = (unsigned short*)p;  p += szX;
    unsigned short* Km = (unsigned short*)p;  p += szX;
    unsigned short* VT = (unsigned short*)p;  p += szX;  // [F][BS]
    unsigned short* E = (unsigned short*)p;   p += szE;  // [Bz][S][S]
    float* q2 = (float*)p;   p += (size_t)BS * 4;
    float* k2 = (float*)p;   p += (size_t)BS * 4;
    float* lsum = (float*)p; p += (size_t)BS * 4;
    if ((size_t)(p - (char*)d_ws) > ws_size) return;  // ~164 MiB scratch required

    const float invs = 1.0f / sqrtf(768.0f);

    // 1) casts
    castk<<<(BS * D / 4 + 255) / 256, 256, 0, stream>>>(x, xb, BS * D / 4);
    castk<<<(F * D / 4 + 255) / 256, 256, 0, stream>>>(Wq, Wqb, F * D / 4);
    castk<<<(F * D / 4 + 255) / 256, 256, 0, stream>>>(Wk, Wkb, F * D / 4);
    castk<<<(F * D / 4 + 255) / 256, 256, 0, stream>>>(Wv, Wvb, F * D / 4);

    // 2) Q,K = x . W^T  (z=0 -> Wq, z=1 -> Wk)
    gemm256<0><<<dim3(F / 256, BS / 256, 2), 512, 0, stream>>>(
        xb, D, 0,
        Wqb, D, (long long)F * D,
        Qm, F, (long long)BS * F,
        D, nullptr, 0, nullptr, 0, 0.f);

    //    V^T = Wv . x^T   -> VT[f][s]
    gemm256<0><<<dim3(BS / 256, F / 256, 1), 512, 0, stream>>>(
        Wvb, D, 0,
        xb, D, 0,
        VT, BS, 0,
        D, nullptr, 0, nullptr, 0, 0.f);

    // 3) row norms of Q,K
    rowreduce<1><<<BS / 4, 256, 0, stream>>>(Qm, F, BS, q2);
    rowreduce<1><<<BS / 4, 256, 0, stream>>>(Km, F, BS, k2);

    // 4) E = exp(sqrt(max(q2+k2-2*Q.K^T,0))*invs)
    gemm256<1><<<dim3(S / 256, S / 256, Bz), 512, 0, stream>>>(
        Qm, F, (long long)S * F,
        Km, F, (long long)S * F,
        E, S, (long long)S * S,
        F, q2, S, k2, S, invs);

    // 5) l = rowsum(E)
    rowreduce<0><<<BS / 4, 256, 0, stream>>>(E, S, BS, lsum);

    // 6) out = (E . V) / l
    gemm256<2><<<dim3(F / 256, S / 256, Bz), 512, 0, stream>>>(
        E, S, (long long)S * S,
        VT, BS, (long long)S,
        d_out, F, (long long)S * F,
        S, lsum, S, nullptr, 0, 0.f);
}

// Round 4
// 262.173 us; speedup vs baseline: 1.3620x; 1.2365x over previous
//
#include <hip/hip_runtime.h>
#include <stdint.h>
#include <math.h>

// cdist-attention, bf16 MFMA pipeline, m201-style 8-phase 256x256 GEMM:
//   castk:         fp32 -> bf16 (RNE)
//   gemm256<0>:    C_bf16 = A(MxK) . B(NxK)^T
//   rowreduce<1>:  row sum-of-squares (q2,k2)
//   gemm256<1>:    E = exp(sqrt(max(q2+k2-2*QK,0))/sqrt(768)) as bf16
//   rowreduce<0>:  l = rowsum(E)
//   gemm256<2>:    out_f32 = (E . V) / l
//
// GEMM core: BM=BN=256, BK=64 double-buffered (128 KiB LDS), 8 waves (2Mx4N,
// 128x64 C/wave). 4 phases/K-tile: {asm ds_read_b128 frags; stage 1 half-tile
// (global_load_lds w16); barrier; lgkmcnt(0)+sched_barrier; setprio(1); 16 MFMA;
// setprio(0); barrier}. Counted vmcnt(6) once per K-tile.
//
// RACE-SAFE STAGING (R3 bug fix): staging halves == per-phase read-union sets.
//   A-half h = rows { (row>>6)&1 == h }   (aF reads half0 in P1, aH half1 in P3)
//   B-half h = rows { (row>>5)&1 == h }   (bL reads half0 in P1, bH half1 in P2)
// Per tile t (buf b): P1 stages Bh1(t+1)->b^1; P2 Ah0(t+2)->b (dead since P1);
// P3 Bh0(t+2)->b (dead since P1); P4 Ah1(t+2)->b (dead since P3). Every target
// region's last ds_read completed before a post-MFMA barrier preceding issue.

typedef __attribute__((ext_vector_type(8))) __bf16 bf16x8;
typedef __attribute__((ext_vector_type(4))) float f32x4;

__device__ __forceinline__ unsigned short f2b(float f) {
    unsigned u = __float_as_uint(f);
    unsigned r = 0x7fffu + ((u >> 16) & 1u);
    return (unsigned short)((u + r) >> 16);
}
__device__ __forceinline__ float b2f(unsigned short h) {
    return __uint_as_float(((unsigned)h) << 16);
}

__device__ __forceinline__ void wg_barrier() {
    asm volatile("" ::: "memory");
    __builtin_amdgcn_s_barrier();
    asm volatile("" ::: "memory");
}

__device__ __forceinline__ void glds16(const unsigned short* src, unsigned short* dst) {
    __builtin_amdgcn_global_load_lds(
        (const __attribute__((address_space(1))) unsigned int*)src,
        (__attribute__((address_space(3))) unsigned int*)dst, 16, 0, 0);
}

__device__ __forceinline__ unsigned lds_off(const void* p) {
    return (unsigned)(uintptr_t)(const __attribute__((address_space(3))) char*)p;
}

__global__ __launch_bounds__(256) void castk(const float* __restrict__ src,
                                             unsigned short* __restrict__ dst, int n4) {
    int i = blockIdx.x * 256 + threadIdx.x;
    if (i >= n4) return;
    float4 v = ((const float4*)src)[i];
    ushort4 o;
    o.x = f2b(v.x); o.y = f2b(v.y); o.z = f2b(v.z); o.w = f2b(v.w);
    ((ushort4*)dst)[i] = o;
}

// MODE 0: row sum; MODE 1: row sum of squares. One wave per row.
template <int MODE>
__global__ __launch_bounds__(256) void rowreduce(const unsigned short* __restrict__ X,
                                                 int L, int rows, float* __restrict__ out) {
    int w = threadIdx.x >> 6, lane = threadIdx.x & 63;
    int row = blockIdx.x * 4 + w;
    if (row >= rows) return;
    const unsigned short* xr = X + (size_t)row * L;
    float s = 0.f;
    int passes = L >> 8;
    for (int p = 0; p < passes; ++p) {
        ushort4 u = *(const ushort4*)(xr + (p << 8) + lane * 4);
        float a = b2f(u.x), b = b2f(u.y), c = b2f(u.z), d = b2f(u.w);
        s += MODE ? (a * a + b * b + c * c + d * d) : (a + b + c + d);
    }
#pragma unroll
    for (int o = 32; o > 0; o >>= 1) s += __shfl_down(s, o);
    if (lane == 0) out[row] = s;
}

#define MF(A_, B_, C_) (C_) = __builtin_amdgcn_mfma_f32_16x16x32_bf16((A_), (B_), (C_), 0, 0, 0)
#define DSR(dst_, a_, imm_) \
    asm volatile("ds_read_b128 %0, %1 offset:" #imm_ : "=v"(dst_) : "v"(a_))
#define LGKM(n_) asm volatile("s_waitcnt lgkmcnt(" #n_ ")" ::: "memory")
#define VMC6 asm volatile("s_waitcnt vmcnt(6)" ::: "memory")
#define VMC0 asm volatile("s_waitcnt vmcnt(0)" ::: "memory")
#define SB0 __builtin_amdgcn_sched_barrier(0)
#define NOPS ((void)0)

#define CLUSTER(MI0_, NI0_, AARR_, BARR_)                                  \
    _Pragma("unroll") for (int mi_ = 0; mi_ < 4; ++mi_) {                  \
        _Pragma("unroll") for (int ni_ = 0; ni_ < 2; ++ni_) {              \
            MF(AARR_[mi_][0], BARR_[ni_][0], acc[(MI0_) + mi_][(NI0_) + ni_]); \
            MF(AARR_[mi_][1], BARR_[ni_][1], acc[(MI0_) + mi_][(NI0_) + ni_]); \
        }                                                                  \
    }

// One K-tile = 4 phases. S1..S4 are staging statements; VMW_ the boundary wait.
#define TILE(A0_, A0X_, B0_, B0X_, S1_, S2_, S3_, S4_, VMW_) do {          \
    DSR(aF[0][0], A0_, 0);    DSR(aF[0][1], A0X_, 0);                      \
    DSR(aF[1][0], A0_, 2048); DSR(aF[1][1], A0X_, 2048);                   \
    DSR(aF[2][0], A0_, 4096); DSR(aF[2][1], A0X_, 4096);                   \
    DSR(aF[3][0], A0_, 6144); DSR(aF[3][1], A0X_, 6144);                   \
    DSR(bL[0][0], B0_, 0);    DSR(bL[0][1], B0X_, 0);                      \
    DSR(bL[1][0], B0_, 2048); DSR(bL[1][1], B0X_, 2048);                   \
    S1_;                                                                   \
    LGKM(8);                                                               \
    wg_barrier();                                                          \
    LGKM(0); SB0;                                                          \
    __builtin_amdgcn_s_setprio(1);                                         \
    CLUSTER(0, 0, aF, bL)                                                  \
    SB0; __builtin_amdgcn_s_setprio(0);                                    \
    wg_barrier();                                                          \
    DSR(bH[0][0], B0_, 4096); DSR(bH[0][1], B0X_, 4096);                   \
    DSR(bH[1][0], B0_, 6144); DSR(bH[1][1], B0X_, 6144);                   \
    S2_;                                                                   \
    wg_barrier();                                                          \
    LGKM(0); SB0;                                                          \
    __builtin_amdgcn_s_setprio(1);                                         \
    CLUSTER(0, 2, aF, bH)                                                  \
    SB0; __builtin_amdgcn_s_setprio(0);                                    \
    wg_barrier();                                                          \
    DSR(aH[0][0], A0_, 8192);  DSR(aH[0][1], A0X_, 8192);                  \
    DSR(aH[1][0], A0_, 10240); DSR(aH[1][1], A0X_, 10240);                 \
    DSR(aH[2][0], A0_, 12288); DSR(aH[2][1], A0X_, 12288);                 \
    DSR(aH[3][0], A0_, 14336); DSR(aH[3][1], A0X_, 14336);                 \
    S3_;                                                                   \
    wg_barrier();                                                          \
    LGKM(0); SB0;                                                          \
    __builtin_amdgcn_s_setprio(1);                                         \
    CLUSTER(4, 2, aH, bH)                                                  \
    SB0; __builtin_amdgcn_s_setprio(0);                                    \
    wg_barrier();                                                          \
    S4_;                                                                   \
    VMW_;                                                                  \
    wg_barrier();                                                          \
    SB0;                                                                   \
    __builtin_amdgcn_s_setprio(1);                                         \
    CLUSTER(4, 0, aH, bL)                                                  \
    SB0; __builtin_amdgcn_s_setprio(0);                                    \
    wg_barrier();                                                          \
} while (0)

// Stage A-half H of K-tile T into buffer BUF.
// Thread stages rows (lr0 + H*64) and (lr0 + H*64 + 128); LDS dst linear.
#define SA_(T_, BUF_, H_) do {                                             \
    const unsigned short* s_ = pA0 + (size_t)((H_) * 64) * lda + (size_t)(T_) * 64; \
    unsigned short* d_ = As + (BUF_) * 16384 + (H_) * 4096 + tid * 8;      \
    glds16(s_, d_);                                                        \
    glds16(s_ + (size_t)128 * lda, d_ + 8192);                             \
} while (0)
// Stage B-half H (32-row interleave): rows (lr0+(lr0&32) + H*32) and +128.
#define SBs_(T_, BUF_, H_) do {                                            \
    const unsigned short* s_ = pB0 + (size_t)((H_) * 32) * ldb + (size_t)(T_) * 64; \
    unsigned short* d_ = Bs + (BUF_) * 16384 + (H_) * 2048 + dB0 + tid * 8; \
    glds16(s_, d_);                                                        \
    glds16(s_ + (size_t)128 * ldb, d_ + 8192);                             \
} while (0)

// C[m][n] = sum_k A[m][k]*B[n][k].
// EPI 0: store bf16.  EPI 1: scores epilogue.  EPI 2: store f32 = acc/aux1[row].
template <int EPI>
__global__ __launch_bounds__(512, 2) void gemm256(
    const unsigned short* __restrict__ A, int lda, long long sA,
    const unsigned short* __restrict__ B, int ldb, long long sB,
    void* __restrict__ Cv, int ldc, long long sC,
    int Kd,
    const float* __restrict__ aux1, int sAux1,
    const float* __restrict__ aux2, int sAux2,
    float invs) {
    // [2 buf][256 rows][64 k] each, chunk-swizzled; 128-B aligned for ^0x40 trick
    __shared__ __attribute__((aligned(128))) unsigned short As[2 * 256 * 64];
    __shared__ __attribute__((aligned(128))) unsigned short Bs[2 * 256 * 64];

    const int z = blockIdx.z;
    const unsigned short* __restrict__ Ab = A + (size_t)z * sA;
    const unsigned short* __restrict__ Bb = B + (size_t)z * sB;
    const int i0 = blockIdx.y * 256;
    const int j0 = blockIdx.x * 256;
    const int tid = threadIdx.x;
    const int w = tid >> 6, lane = tid & 63;
    const int wr = w >> 2, wc = w & 3;          // 2 x 4 wave grid
    const int c16 = lane & 15, kq = lane >> 4;  // frag col / k-octet

    // staging source (pre-swizzled global chunk; LDS dst stays linear)
    const int lr0 = tid >> 3;                    // 0..63
    const int clog0 = (tid & 7) ^ (lr0 & 7);     // logical 16B chunk
    const unsigned short* pA0 = Ab + (size_t)(i0 + lr0) * lda + clog0 * 8;
    const unsigned short* pB0 = Bb + (size_t)(j0 + lr0 + (lr0 & 32)) * ldb + clog0 * 8;
    const int dB0 = (tid & 256) << 3;  // +2048 shorts for tid>=256 (row group +64)

    // frag read bases (swizzled): stored chunk = (kk*4+kq) ^ (row&7); row&7==c16&7
    const int swc = (kq ^ (c16 & 7)) << 4;
    const unsigned adrA0 = lds_off(As) + (unsigned)(wr * 128 + c16) * 128 + swc;
    const unsigned adrA0x = adrA0 ^ 64u;
    const unsigned adrA1 = adrA0 + 32768u, adrA1x = adrA0x + 32768u;
    const unsigned adrB0 = lds_off(Bs) + (unsigned)(wc * 64 + c16) * 128 + swc;
    const unsigned adrB0x = adrB0 ^ 64u;
    const unsigned adrB1 = adrB0 + 32768u, adrB1x = adrB0x + 32768u;

    f32x4 acc[8][4];
    const f32x4 zero = {0.f, 0.f, 0.f, 0.f};
#pragma unroll
    for (int i = 0; i < 8; ++i)
#pragma unroll
        for (int j = 0; j < 4; ++j) acc[i][j] = zero;

    bf16x8 aF[4][2], aH[4][2], bL[2][2], bH[2][2];

    const int npairs = Kd >> 7;  // BK=64 tile pairs; requires Kd % 128 == 0, >= 2

    // prologue: tile0 all 4 halves (buf0); tile1 Ah0,Bh0,Ah1 (buf1); vmcnt(6)
    // retires all 8 tile0 loads, leaves {Ah0,Bh0,Ah1}(t1) in flight (invariant).
    SA_(0, 0, 0); SA_(0, 0, 1); SBs_(0, 0, 0); SBs_(0, 0, 1);
    SA_(1, 1, 0); SBs_(1, 1, 0); SA_(1, 1, 1);
    VMC6;
    wg_barrier();

    for (int u = 0; u < npairs - 1; ++u) {
        const int t0 = 2 * u;
        TILE(adrA0, adrA0x, adrB0, adrB0x,
             SBs_(t0 + 1, 1, 1), SA_(t0 + 2, 0, 0), SBs_(t0 + 2, 0, 0), SA_(t0 + 2, 0, 1),
             VMC6);
        TILE(adrA1, adrA1x, adrB1, adrB1x,
             SBs_(t0 + 2, 0, 1), SA_(t0 + 3, 1, 0), SBs_(t0 + 3, 1, 0), SA_(t0 + 3, 1, 1),
             VMC6);
    }
    {   // tail pair: finish Bh1(last tile); drain; last tile pure compute
        const int t0 = 2 * npairs - 2;
        TILE(adrA0, adrA0x, adrB0, adrB0x,
             SBs_(t0 + 1, 1, 1), NOPS, NOPS, NOPS, VMC0);
        TILE(adrA1, adrA1x, adrB1, adrB1x, NOPS, NOPS, NOPS, NOPS, NOPS);
    }

    // C/D layout: col = lane&15, row = (lane>>4)*4 + reg
    const int r4 = kq * 4;
    if constexpr (EPI == 0) {
        unsigned short* C = (unsigned short*)Cv + (size_t)z * sC;
#pragma unroll
        for (int mi = 0; mi < 8; ++mi)
#pragma unroll
            for (int ni = 0; ni < 4; ++ni) {
                const int row = i0 + wr * 128 + mi * 16 + r4;
                const int col = j0 + wc * 64 + ni * 16 + c16;
#pragma unroll
                for (int r = 0; r < 4; ++r)
                    C[(size_t)(row + r) * ldc + col] = f2b(acc[mi][ni][r]);
            }
    } else if constexpr (EPI == 1) {
        unsigned short* C = (unsigned short*)Cv + (size_t)z * sC;
        const float* q2b = aux1 + (size_t)z * sAux1;
        const float* k2b = aux2 + (size_t)z * sAux2;
#pragma unroll
        for (int mi = 0; mi < 8; ++mi)
#pragma unroll
            for (int ni = 0; ni < 4; ++ni) {
                const int row = i0 + wr * 128 + mi * 16 + r4;
                const int col = j0 + wc * 64 + ni * 16 + c16;
                const float k2v = k2b[col];
#pragma unroll
                for (int r = 0; r < 4; ++r) {
                    float d2 = q2b[row + r] + k2v - 2.0f * acc[mi][ni][r];
                    float e = __expf(sqrtf(fmaxf(d2, 0.f)) * invs);
                    C[(size_t)(row + r) * ldc + col] = f2b(e);
                }
            }
    } else {
        float* C = (float*)Cv + (size_t)z * sC;
        const float* lb = aux1 + (size_t)z * sAux1;
#pragma unroll
        for (int mi = 0; mi < 8; ++mi)
#pragma unroll
            for (int ni = 0; ni < 4; ++ni) {
                const int row = i0 + wr * 128 + mi * 16 + r4;
                const int col = j0 + wc * 64 + ni * 16 + c16;
#pragma unroll
                for (int r = 0; r < 4; ++r)
                    C[(size_t)(row + r) * ldc + col] = acc[mi][ni][r] / lb[row + r];
            }
    }
}

extern "C" void kernel_launch(void* const* d_in, const int* in_sizes, int n_in,
                              void* d_out, int out_size, void* d_ws, size_t ws_size,
                              hipStream_t stream) {
    const float* x = (const float*)d_in[0];
    const float* Wq = (const float*)d_in[1];
    const float* Wk = (const float*)d_in[2];
    const float* Wv = (const float*)d_in[3];
    const int Bz = 8, S = 2048, D = 768, F = 768;
    const int BS = Bz * S;  // 16384

    const size_t szX = (size_t)BS * D * 2;
    const size_t szW = (size_t)F * D * 2;
    const size_t szE = (size_t)Bz * S * S * 2;

    char* p = (char*)d_ws;
    unsigned short* xb = (unsigned short*)p;  p += szX;
    unsigned short* Wqb = (unsigned short*)p; p += szW;
    unsigned short* Wkb = (unsigned short*)p; p += szW;
    unsigned short* Wvb = (unsigned short*)p; p += szW;
    unsigned short* Qm = (unsigned short*)p;  p += szX;
    unsigned short* Km = (unsigned short*)p;  p += szX;
    unsigned short* VT = (unsigned short*)p;  p += szX;  // [F][BS]
    unsigned short* E = (unsigned short*)p;   p += szE;  // [Bz][S][S]
    float* q2 = (float*)p;   p += (size_t)BS * 4;
    float* k2 = (float*)p;   p += (size_t)BS * 4;
    float* lsum = (float*)p; p += (size_t)BS * 4;
    if ((size_t)(p - (char*)d_ws) > ws_size) return;  // ~164 MiB scratch required

    const float invs = 1.0f / sqrtf(768.0f);

    // 1) casts
    castk<<<(BS * D / 4 + 255) / 256, 256, 0, stream>>>(x, xb, BS * D / 4);
    castk<<<(F * D / 4 + 255) / 256, 256, 0, stream>>>(Wq, Wqb, F * D / 4);
    castk<<<(F * D / 4 + 255) / 256, 256, 0, stream>>>(Wk, Wkb, F * D / 4);
    castk<<<(F * D / 4 + 255) / 256, 256, 0, stream>>>(Wv, Wvb, F * D / 4);

    // 2) Q,K = x . W^T  (z=0 -> Wq, z=1 -> Wk)
    gemm256<0><<<dim3(F / 256, BS / 256, 2), 512, 0, stream>>>(
        xb, D, 0,
        Wqb, D, (long long)F * D,
        Qm, F, (long long)BS * F,
        D, nullptr, 0, nullptr, 0, 0.f);

    //    V^T = Wv . x^T   -> VT[f][s]
    gemm256<0><<<dim3(BS / 256, F / 256, 1), 512, 0, stream>>>(
        Wvb, D, 0,
        xb, D, 0,
        VT, BS, 0,
        D, nullptr, 0, nullptr, 0, 0.f);

    // 3) row norms of Q,K
    rowreduce<1><<<BS / 4, 256, 0, stream>>>(Qm, F, BS, q2);
    rowreduce<1><<<BS / 4, 256, 0, stream>>>(Km, F, BS, k2);

    // 4) E = exp(sqrt(max(q2+k2-2*Q.K^T,0))*invs)
    gemm256<1><<<dim3(S / 256, S / 256, Bz), 512, 0, stream>>>(
        Qm, F, (long long)S * F,
        Km, F, (long long)S * F,
        E, S, (long long)S * S,
        F, q2, S, k2, S, invs);

    // 5) l = rowsum(E)
    rowreduce<0><<<BS / 4, 256, 0, stream>>>(E, S, BS, lsum);

    // 6) out = (E . V) / l
    gemm256<2><<<dim3(F / 256, S / 256, Bz), 512, 0, stream>>>(
        E, S, (long long)S * S,
        VT, BS, (long long)S,
        d_out, F, (long long)S * F,
        S, lsum, S, nullptr, 0, 0.f);
}